// Round 3
// baseline (278.808 us; speedup 1.0000x reference)
//
#include <hip/hip_runtime.h>
#include <cstdint>
#include <cstddef>

// ---------------------------------------------------------------------------
// MHA: out = softmax(causal(mask((XWq)(XWk)^T/8))) (XWv) Wo + biases
// B=2, T=2048, D=1024, H=16, dk=64. bf16 MFMA, fp32 accumulate.
// R3: causal-balanced attention (block = q-chunk pair {p, 31-p}, kv streamed
//     once, K/V frags shared by both chunks), double-buffered KV staging with
//     post-barrier prefetch; GEMMs moved to m97 128x128/4x4 structure;
//     cvt pointer-array scratch fixed.
// ---------------------------------------------------------------------------

typedef __bf16 bf16x8 __attribute__((ext_vector_type(8)));
typedef float f32x4 __attribute__((ext_vector_type(4)));

#define MFMA(a, b, c) __builtin_amdgcn_mfma_f32_16x16x32_bf16((a), (b), (c), 0, 0, 0)

static constexpr int D_MODEL = 1024;
static constexpr int T_ = 2048;
static constexpr int M_TOK = 4096;   // B*T

__device__ __forceinline__ unsigned short f32_to_bf16(float f) {   // RNE
    union { float f; uint32_t u; } v; v.f = f;
    uint32_t u = v.u;
    uint32_t r = u + 0x7fffu + ((u >> 16) & 1u);
    return (unsigned short)(r >> 16);
}
__device__ __forceinline__ unsigned short f32_to_bf16_fast(float f) { // half-up
    union { float f; uint32_t u; } v; v.f = f;
    return (unsigned short)((v.u + 0x8000u) >> 16);
}

typedef __attribute__((address_space(1))) void* as1_ptr;
typedef __attribute__((address_space(3))) void* as3_ptr;
__device__ __forceinline__ void gload_lds16(const void* g, void* l) {
    // lane's 16B land at (wave-uniform l) + lane*16
    __builtin_amdgcn_global_load_lds((as1_ptr)(void*)g, (as3_ptr)l, 16, 0, 0);
}

// --------------------------- fused fp32 -> bf16 convert ---------------------
// dst (float4 units): q[0,1M) k[1M,2M) v[2M,3M) Wq Wk Wv Wo [3M..4M)
__global__ __launch_bounds__(256) void cvt_all(
    const float* __restrict__ q, const float* __restrict__ k,
    const float* __restrict__ v, const float* __restrict__ wq,
    const float* __restrict__ wk, const float* __restrict__ wv,
    const float* __restrict__ wo, ushort4* __restrict__ dst) {
    int i = blockIdx.x * blockDim.x + threadIdx.x;
    constexpr int R = 1 << 20;        // 1M float4 per token tensor
    const float* s;
    int idx;
    if (i < 3 * R) {
        s = (i < R) ? q : (i < 2 * R) ? k : v;
        idx = i & (R - 1);
    } else {
        int j = i - 3 * R;
        int w = j >> 18;
        s = (w == 0) ? wq : (w == 1) ? wk : (w == 2) ? wv : wo;
        idx = j & ((1 << 18) - 1);
    }
    float4 f = ((const float4*)s)[idx];
    ushort4 o;
    o.x = f32_to_bf16(f.x); o.y = f32_to_bf16(f.y);
    o.z = f32_to_bf16(f.z); o.w = f32_to_bf16(f.w);
    dst[i] = o;
}

// --------------------------- GEMM: C = A @ W^T + bias -----------------------
// m97 structure: 128x128 tile, BK=64, 4 waves 2x2, 64x64 per wave (4x4 frags),
// LDS single-buffered 2-barrier, global_load_lds(16B), XOR swizzle.
// MODE 0: bf16 out [B][H][T][64]; MODE 2: bf16 out [B][H][64][T]; MODE 3: f32 [M][D]
template<int MODE>
__device__ __forceinline__ void gemm_body(
    const unsigned short* __restrict__ A, const unsigned short* __restrict__ W,
    const float* __restrict__ bias, void* __restrict__ outp,
    unsigned short* As, unsigned short* Ws, int bx, int by)
{
    const int tid = threadIdx.x;
    const int lane = tid & 63, wave = tid >> 6;
    const int wm = wave >> 1, wn = wave & 1;
    const int r16 = lane & 15, kg = lane >> 4;
    const int m_blk = by * 128, n_blk = bx * 128;

    f32x4 acc[4][4];
    #pragma unroll
    for (int mt = 0; mt < 4; ++mt)
        #pragma unroll
        for (int nt = 0; nt < 4; ++nt) acc[mt][nt] = (f32x4){0, 0, 0, 0};

    for (int k0 = 0; k0 < D_MODEL; k0 += 64) {
        __syncthreads();
        #pragma unroll
        for (int j = 0; j < 4; ++j) {           // A tile: 128x64 = 16 KB
            int si = j * 256 + tid;
            int row = si >> 3, cg = (si & 7) ^ (row & 7);
            gload_lds16(A + (size_t)(m_blk + row) * D_MODEL + k0 + cg * 8,
                        (char*)As + (j * 256 + wave * 64) * 16);
        }
        #pragma unroll
        for (int j = 0; j < 4; ++j) {           // W tile: 128x64 = 16 KB
            int si = j * 256 + tid;
            int row = si >> 3, cg = (si & 7) ^ (row & 7);
            gload_lds16(W + (size_t)(n_blk + row) * D_MODEL + k0 + cg * 8,
                        (char*)Ws + (j * 256 + wave * 64) * 16);
        }
        __syncthreads();                        // drains vmcnt
        #pragma unroll
        for (int kc = 0; kc < 2; ++kc) {
            bf16x8 af[4], wf[4];
            #pragma unroll
            for (int mt = 0; mt < 4; ++mt) {
                int row = wm * 64 + mt * 16 + r16;
                af[mt] = *(const bf16x8*)(As + row * 64 + (((kc * 4 + kg) ^ (row & 7)) * 8));
            }
            #pragma unroll
            for (int nt = 0; nt < 4; ++nt) {
                int row = wn * 64 + nt * 16 + r16;
                wf[nt] = *(const bf16x8*)(Ws + row * 64 + (((kc * 4 + kg) ^ (row & 7)) * 8));
            }
            #pragma unroll
            for (int mt = 0; mt < 4; ++mt)
                #pragma unroll
                for (int nt = 0; nt < 4; ++nt)
                    acc[mt][nt] = MFMA(af[mt], wf[nt], acc[mt][nt]);
        }
    }
    // epilogue: C/D layout col=lane&15, row=kg*4+reg
    #pragma unroll
    for (int nt = 0; nt < 4; ++nt) {
        int n = n_blk + wn * 64 + nt * 16 + r16;
        float bn = bias[n];
        #pragma unroll
        for (int mt = 0; mt < 4; ++mt)
            #pragma unroll
            for (int r = 0; r < 4; ++r) {
                int m = m_blk + wm * 64 + mt * 16 + kg * 4 + r;
                float vv = acc[mt][nt][r] + bn;
                if (MODE == 3) {
                    ((float*)outp)[(size_t)m * D_MODEL + n] = vv;
                } else {
                    int b = m >> 11, t = m & 2047, h = n >> 6, dki = n & 63;
                    unsigned short* o = (unsigned short*)outp;
                    if (MODE == 0)
                        o[((size_t)(b * 16 + h) * 2048 + t) * 64 + dki] = f32_to_bf16(vv);
                    else
                        o[((size_t)(b * 16 + h) * 64 + dki) * 2048 + t] = f32_to_bf16(vv);
                }
            }
    }
}

__global__ __launch_bounds__(256) void gemm_qkv(
    const unsigned short* __restrict__ qb, const unsigned short* __restrict__ kb,
    const unsigned short* __restrict__ vb, const unsigned short* __restrict__ Wqb,
    const unsigned short* __restrict__ Wkb, const unsigned short* __restrict__ Wvb,
    const float* __restrict__ bq, const float* __restrict__ bk, const float* __restrict__ bv,
    unsigned short* __restrict__ Qhp, unsigned short* __restrict__ Khp,
    unsigned short* __restrict__ Vtp)
{
    __shared__ __align__(16) unsigned short As[128 * 64];
    __shared__ __align__(16) unsigned short Ws[128 * 64];
    const int z = blockIdx.z;
    const unsigned short* A = (z == 0) ? qb : (z == 1) ? kb : vb;
    const unsigned short* W = (z == 0) ? Wqb : (z == 1) ? Wkb : Wvb;
    const float* bias = (z == 0) ? bq : (z == 1) ? bk : bv;
    if (z < 2)
        gemm_body<0>(A, W, bias, (z == 0) ? (void*)Qhp : (void*)Khp, As, Ws,
                     blockIdx.x, blockIdx.y);
    else
        gemm_body<2>(A, W, bias, (void*)Vtp, As, Ws, blockIdx.x, blockIdx.y);
}

__global__ __launch_bounds__(256) void gemm_out(
    const unsigned short* __restrict__ ab, const unsigned short* __restrict__ Wob,
    const float* __restrict__ bo, float* __restrict__ outp)
{
    __shared__ __align__(16) unsigned short As[128 * 64];
    __shared__ __align__(16) unsigned short Ws[128 * 64];
    gemm_body<3>(ab, Wob, bo, (void*)outp, As, Ws, blockIdx.x, blockIdx.y);
}

// --------------------------- flash attention --------------------------------
// Block = 4 waves, owns the q-chunk PAIR {p, 31-p} (64 rows each; each wave
// handles 16 rows of chunk A and 16 of chunk B). kv streamed ONCE 0..31-p:
// uniform 33 active chunk-steps per block, K/V frag reads shared by both
// chunks. KV LDS double-buffered; prefetch issued AFTER the barrier so the
// global_load_lds flies during compute (vmcnt drain lands at next barrier).
__global__ __launch_bounds__(256) void attn_fwd(
    const unsigned short* __restrict__ Qh, const unsigned short* __restrict__ Kh,
    const unsigned short* __restrict__ Vt, const int* __restrict__ mask,
    const int* __restrict__ causal_p, unsigned short* __restrict__ attnout)
{
    __shared__ __align__(16) unsigned short Ks[2][64 * 64];   // [key][dk] swz
    __shared__ __align__(16) unsigned short Vs[2][64 * 64];   // [dk][key] swz
    __shared__ __align__(16) unsigned short PsA[4][16 * 64];  // per-wave P swz
    __shared__ __align__(16) unsigned short PsB[4][16 * 64];

    const int tid = threadIdx.x;
    const int lane = tid & 63, wave = tid >> 6;
    const int p = blockIdx.x, bh = blockIdx.y;
    const int b = bh >> 4, h = bh & 15;
    const int causal = *causal_p;
    const int r16 = lane & 15, kg = lane >> 4;

    const int qcA = p, qcB = 31 - p;
    const int q0A = qcA * 64 + wave * 16;
    const int q0B = qcB * 64 + wave * 16;

    const unsigned short* Qb = Qh + (size_t)bh * T_ * 64;
    const unsigned short* Kb = Kh + (size_t)bh * T_ * 64;
    const unsigned short* Vb = Vt + (size_t)bh * 64 * T_;
    const int* mb = mask + b * T_;

    bf16x8 qfA0 = *(const bf16x8*)(Qb + (size_t)(q0A + r16) * 64 + kg * 8);
    bf16x8 qfA1 = *(const bf16x8*)(Qb + (size_t)(q0A + r16) * 64 + 32 + kg * 8);
    bf16x8 qfB0 = *(const bf16x8*)(Qb + (size_t)(q0B + r16) * 64 + kg * 8);
    bf16x8 qfB1 = *(const bf16x8*)(Qb + (size_t)(q0B + r16) * 64 + 32 + kg * 8);

    float laccA[4] = {0, 0, 0, 0}, laccB[4] = {0, 0, 0, 0};
    f32x4 oA[4], oB[4];
    #pragma unroll
    for (int f = 0; f < 4; ++f) { oA[f] = (f32x4){0,0,0,0}; oB[f] = (f32x4){0,0,0,0}; }
    const float sc2 = 0.18033688011112042f;   // log2(e) / sqrt(64)

    const int nT = causal ? (qcB + 1) : 32;

    // stage(buf, t): K tile [t0..t0+63][0..63], V tile [0..63][t0..t0+63]
    auto stage = [&](int buf, int t) {
        int t0 = t * 64;
        #pragma unroll
        for (int j = 0; j < 2; ++j) {
            int si = j * 256 + tid;
            int row = si >> 3, cg = (si & 7) ^ (row & 7);
            gload_lds16(Kb + (size_t)(t0 + row) * 64 + cg * 8,
                        (char*)Ks[buf] + (j * 256 + wave * 64) * 16);
            gload_lds16(Vb + (size_t)row * T_ + t0 + cg * 8,
                        (char*)Vs[buf] + (j * 256 + wave * 64) * 16);
        }
    };

    stage(0, 0);
    for (int t = 0; t < nT; ++t) {
        __syncthreads();              // stage(t) complete (drains each wave's vmcnt)
        if (t + 1 < nT) stage((t + 1) & 1, t + 1);   // async prefetch over compute
        const unsigned short* Kst = Ks[t & 1];
        const unsigned short* Vst = Vs[t & 1];
        const int t0 = t * 64;
        const bool activeA = !causal || (t <= qcA);          // block-uniform
        const bool needcA = causal && (t == qcA);
        const bool needcB = causal && (t == qcB);

        // ---- S = Q K^T, K frags shared between chunks ----
        f32x4 sA[4], sB[4];
        #pragma unroll
        for (int c = 0; c < 4; ++c) {
            int key = c * 16 + r16;
            bf16x8 kf0 = *(const bf16x8*)(Kst + key * 64 + ((kg ^ (key & 7)) * 8));
            bf16x8 kf1 = *(const bf16x8*)(Kst + key * 64 + (((4 + kg) ^ (key & 7)) * 8));
            f32x4 zB = (f32x4){0,0,0,0};
            zB = MFMA(qfB0, kf0, zB);
            zB = MFMA(qfB1, kf1, zB);
            sB[c] = zB;
            if (activeA) {
                f32x4 zA = (f32x4){0,0,0,0};
                zA = MFMA(qfA0, kf0, zA);
                zA = MFMA(qfA1, kf1, zA);
                sA[c] = zA;
            }
        }

        // ---- exp (no max shift; scores bounded) + masks ----
        float pA[4][4], pB[4][4];
        #pragma unroll
        for (int c = 0; c < 4; ++c) {
            int kcol = t0 + c * 16 + r16;
            bool mk = (mb[kcol] != 0);
            #pragma unroll
            for (int r = 0; r < 4; ++r) {
                bool okB = mk && (!needcB || (kcol <= q0B + kg * 4 + r));
                pB[c][r] = okB ? __builtin_amdgcn_exp2f(sB[c][r] * sc2) : 0.f;
            }
            if (activeA) {
                #pragma unroll
                for (int r = 0; r < 4; ++r) {
                    bool okA = mk && (!needcA || (kcol <= q0A + kg * 4 + r));
                    pA[c][r] = okA ? __builtin_amdgcn_exp2f(sA[c][r] * sc2) : 0.f;
                }
            }
        }
        #pragma unroll
        for (int r = 0; r < 4; ++r) {
            laccB[r] += (pB[0][r] + pB[1][r]) + (pB[2][r] + pB[3][r]);
            if (activeA) laccA[r] += (pA[0][r] + pA[1][r]) + (pA[2][r] + pA[3][r]);
        }

        // ---- P: C-layout -> A-layout via per-wave LDS, one wait ----
        unsigned short* pwA = PsA[wave];
        unsigned short* pwB = PsB[wave];
        #pragma unroll
        for (int c = 0; c < 4; ++c)
            #pragma unroll
            for (int r = 0; r < 4; ++r) {
                int row = kg * 4 + r, col = c * 16 + r16;
                int addr = row * 64 + (((col >> 3) ^ (row & 7)) * 8 + (col & 7));
                pwB[addr] = f32_to_bf16_fast(pB[c][r]);
                if (activeA) pwA[addr] = f32_to_bf16_fast(pA[c][r]);
            }
        __asm__ volatile("s_waitcnt lgkmcnt(0)" ::: "memory");
        bf16x8 pfB0 = *(const bf16x8*)(pwB + r16 * 64 + ((kg ^ (r16 & 7)) * 8));
        bf16x8 pfB1 = *(const bf16x8*)(pwB + r16 * 64 + (((4 + kg) ^ (r16 & 7)) * 8));
        bf16x8 pfA0, pfA1;
        if (activeA) {
            pfA0 = *(const bf16x8*)(pwA + r16 * 64 + ((kg ^ (r16 & 7)) * 8));
            pfA1 = *(const bf16x8*)(pwA + r16 * 64 + (((4 + kg) ^ (r16 & 7)) * 8));
        }

        // ---- O += P V, V frags shared between chunks ----
        #pragma unroll
        for (int f = 0; f < 4; ++f) {
            int n = f * 16 + r16;
            bf16x8 vf0 = *(const bf16x8*)(Vst + n * 64 + ((kg ^ (n & 7)) * 8));
            bf16x8 vf1 = *(const bf16x8*)(Vst + n * 64 + (((4 + kg) ^ (n & 7)) * 8));
            oB[f] = MFMA(pfB0, vf0, oB[f]);
            oB[f] = MFMA(pfB1, vf1, oB[f]);
            if (activeA) {
                oA[f] = MFMA(pfA0, vf0, oA[f]);
                oA[f] = MFMA(pfA1, vf1, oA[f]);
            }
        }
    }

    // ---- epilogue: l shuffle tree, store bf16 [B,T,D] for both chunks ----
    #pragma unroll
    for (int r = 0; r < 4; ++r) {
        float lA = laccA[r], lB = laccB[r];
        #pragma unroll
        for (int off = 1; off < 16; off <<= 1) {
            lA += __shfl_xor(lA, off, 64);
            lB += __shfl_xor(lB, off, 64);
        }
        float invA = (lA > 0.f) ? 1.0f / lA : 0.f;
        float invB = (lB > 0.f) ? 1.0f / lB : 0.f;
        size_t baseA = ((size_t)(b * T_ + q0A + kg * 4 + r)) * D_MODEL + h * 64;
        size_t baseB = ((size_t)(b * T_ + q0B + kg * 4 + r)) * D_MODEL + h * 64;
        #pragma unroll
        for (int f = 0; f < 4; ++f) {
            attnout[baseA + f * 16 + r16] = f32_to_bf16(oA[f][r] * invA);
            attnout[baseB + f * 16 + r16] = f32_to_bf16(oB[f][r] * invB);
        }
    }
}

// --------------------------- launch -----------------------------------------
extern "C" void kernel_launch(void* const* d_in, const int* in_sizes, int n_in,
                              void* d_out, int out_size, void* d_ws, size_t ws_size,
                              hipStream_t stream) {
    const float* q  = (const float*)d_in[0];
    const float* k  = (const float*)d_in[1];
    const float* v  = (const float*)d_in[2];
    const float* Wq = (const float*)d_in[3];
    const float* bq = (const float*)d_in[4];
    const float* Wk = (const float*)d_in[5];
    const float* bk = (const float*)d_in[6];
    const float* Wv = (const float*)d_in[7];
    const float* bv = (const float*)d_in[8];
    const float* Wo = (const float*)d_in[9];
    const float* bo = (const float*)d_in[10];
    const int* mask   = (const int*)d_in[11];
    const int* causal = (const int*)d_in[12];

    const size_t SZ_TOK = (size_t)M_TOK * D_MODEL;   // 4M elems
    const size_t SZ_W   = (size_t)D_MODEL * D_MODEL; // 1M elems

    unsigned short* qb  = (unsigned short*)d_ws;
    unsigned short* kb  = qb  + SZ_TOK;
    unsigned short* vb  = kb  + SZ_TOK;
    unsigned short* Wqb = vb  + SZ_TOK;
    unsigned short* Wkb = Wqb + SZ_W;
    unsigned short* Wvb = Wkb + SZ_W;
    unsigned short* Wob = Wvb + SZ_W;
    unsigned short* Qhp = Wob + SZ_W;
    unsigned short* Khp = Qhp + SZ_TOK;
    unsigned short* Vtp = Khp + SZ_TOK;
    unsigned short* ab  = Vtp + SZ_TOK;              // 64 MB total

    cvt_all<<<16384, 256, 0, stream>>>(q, k, v, Wq, Wk, Wv, Wo, (ushort4*)qb);

    gemm_qkv<<<dim3(D_MODEL / 128, M_TOK / 128, 3), 256, 0, stream>>>(
        qb, kb, vb, Wqb, Wkb, Wvb, bq, bk, bv, Qhp, Khp, Vtp);

    attn_fwd<<<dim3(16, 32), 256, 0, stream>>>(Qhp, Khp, Vtp, mask, causal, ab);

    gemm_out<<<dim3(D_MODEL / 128, M_TOK / 128), 256, 0, stream>>>(ab, Wob, bo,
                                                                   (float*)d_out);
}

// Round 5
// 249.417 us; speedup vs baseline: 1.1178x; 1.1178x over previous
//
#include <hip/hip_runtime.h>
#include <cstdint>
#include <cstddef>

// ---------------------------------------------------------------------------
// MHA: out = softmax(causal(mask((XWq)(XWk)^T/8))) (XWv) Wo + biases
// B=2, T=2048, D=1024, H=16, dk=64. bf16 MFMA, fp32 accumulate.
// R5: register-resident P. S^T = mfma(Kfrag, Qfrag) leaves P in C/D layout
//     (lane: key=kg*4+r, q=lane&15); exp2 results are explicitly packed into
//     bf16x8 A-operands for PV using a key-permuted ordering matched by the
//     V fragment construction (two b64 LDS reads per frag). Only the
//     HW-verified 16x16x32 intrinsic is used (R4's 16x16x16 gating broke the
//     host compile pass). No LDS round-trip / lgkmcnt(0) / shuffles in loop.
// ---------------------------------------------------------------------------

typedef __bf16 bf16x8 __attribute__((ext_vector_type(8)));
typedef __bf16 bf16x4 __attribute__((ext_vector_type(4)));
typedef float f32x4 __attribute__((ext_vector_type(4)));

#define MFMA(a, b, c) __builtin_amdgcn_mfma_f32_16x16x32_bf16((a), (b), (c), 0, 0, 0)

static constexpr int D_MODEL = 1024;
static constexpr int T_ = 2048;
static constexpr int M_TOK = 4096;   // B*T

__device__ __forceinline__ unsigned short f32_to_bf16(float f) {   // RNE
    union { float f; uint32_t u; } v; v.f = f;
    uint32_t u = v.u;
    uint32_t r = u + 0x7fffu + ((u >> 16) & 1u);
    return (unsigned short)(r >> 16);
}
__device__ __forceinline__ unsigned f32_to_bf16_fast(float f) {    // half-up
    union { float f; uint32_t u; } v; v.f = f;
    return (v.u + 0x8000u) >> 16;
}

typedef __attribute__((address_space(1))) void* as1_ptr;
typedef __attribute__((address_space(3))) void* as3_ptr;
__device__ __forceinline__ void gload_lds16(const void* g, void* l) {
    // lane's 16B land at (wave-uniform l) + lane*16
    __builtin_amdgcn_global_load_lds((as1_ptr)(void*)g, (as3_ptr)l, 16, 0, 0);
}

// --------------------------- fused fp32 -> bf16 convert ---------------------
// dst (float4 units): q[0,1M) k[1M,2M) v[2M,3M) Wq Wk Wv Wo [3M..4M)
__global__ __launch_bounds__(256) void cvt_all(
    const float* __restrict__ q, const float* __restrict__ k,
    const float* __restrict__ v, const float* __restrict__ wq,
    const float* __restrict__ wk, const float* __restrict__ wv,
    const float* __restrict__ wo, ushort4* __restrict__ dst) {
    int i = blockIdx.x * blockDim.x + threadIdx.x;
    constexpr int R = 1 << 20;        // 1M float4 per token tensor
    const float* s;
    int idx;
    if (i < 3 * R) {
        s = (i < R) ? q : (i < 2 * R) ? k : v;
        idx = i & (R - 1);
    } else {
        int j = i - 3 * R;
        int w = j >> 18;
        s = (w == 0) ? wq : (w == 1) ? wk : (w == 2) ? wv : wo;
        idx = j & ((1 << 18) - 1);
    }
    float4 f = ((const float4*)s)[idx];
    ushort4 o;
    o.x = (unsigned short)f32_to_bf16(f.x); o.y = (unsigned short)f32_to_bf16(f.y);
    o.z = (unsigned short)f32_to_bf16(f.z); o.w = (unsigned short)f32_to_bf16(f.w);
    dst[i] = o;
}

// --------------------------- GEMM: C = A @ W^T + bias -----------------------
// R2 shape (measured faster than 128x128 for K=1024): tile 128x64, BK=64,
// 4 waves 2x2, wave = 64x32 (4x2 frags), global_load_lds(16B), XOR swizzle.
// MODE 0: bf16 out [B][H][T][64]; MODE 2: bf16 out [B][H][64][T]; MODE 3: f32 [M][D]
template<int MODE>
__device__ __forceinline__ void gemm_body(
    const unsigned short* __restrict__ A, const unsigned short* __restrict__ W,
    const float* __restrict__ bias, void* __restrict__ outp,
    unsigned short* As, unsigned short* Ws, int bx, int by)
{
    const int tid = threadIdx.x;
    const int lane = tid & 63, wave = tid >> 6;
    const int wm = wave >> 1, wn = wave & 1;
    const int r16 = lane & 15, kg = lane >> 4;
    const int m_blk = by * 128, n_blk = bx * 64;

    f32x4 acc[4][2];
    #pragma unroll
    for (int mt = 0; mt < 4; ++mt)
        #pragma unroll
        for (int nt = 0; nt < 2; ++nt) acc[mt][nt] = (f32x4){0, 0, 0, 0};

    for (int k0 = 0; k0 < D_MODEL; k0 += 64) {
        __syncthreads();
        #pragma unroll
        for (int j = 0; j < 4; ++j) {           // A tile: 128x64 = 16 KB
            int si = j * 256 + tid;
            int row = si >> 3, cg = (si & 7) ^ (row & 7);
            gload_lds16(A + (size_t)(m_blk + row) * D_MODEL + k0 + cg * 8,
                        (char*)As + (j * 256 + wave * 64) * 16);
        }
        #pragma unroll
        for (int j = 0; j < 2; ++j) {           // W tile: 64x64 = 8 KB
            int si = j * 256 + tid;
            int row = si >> 3, cg = (si & 7) ^ (row & 7);
            gload_lds16(W + (size_t)(n_blk + row) * D_MODEL + k0 + cg * 8,
                        (char*)Ws + (j * 256 + wave * 64) * 16);
        }
        __syncthreads();                        // drains vmcnt
        #pragma unroll
        for (int kc = 0; kc < 2; ++kc) {
            bf16x8 af[4], wf[2];
            #pragma unroll
            for (int mt = 0; mt < 4; ++mt) {
                int row = wm * 64 + mt * 16 + r16;
                af[mt] = *(const bf16x8*)(As + row * 64 + (((kc * 4 + kg) ^ (row & 7)) * 8));
            }
            #pragma unroll
            for (int nt = 0; nt < 2; ++nt) {
                int row = wn * 32 + nt * 16 + r16;
                wf[nt] = *(const bf16x8*)(Ws + row * 64 + (((kc * 4 + kg) ^ (row & 7)) * 8));
            }
            #pragma unroll
            for (int mt = 0; mt < 4; ++mt)
                #pragma unroll
                for (int nt = 0; nt < 2; ++nt)
                    acc[mt][nt] = MFMA(af[mt], wf[nt], acc[mt][nt]);
        }
    }
    // epilogue: C/D layout col=lane&15, row=kg*4+reg
    #pragma unroll
    for (int nt = 0; nt < 2; ++nt) {
        int n = n_blk + wn * 32 + nt * 16 + r16;
        float bn = bias[n];
        #pragma unroll
        for (int mt = 0; mt < 4; ++mt)
            #pragma unroll
            for (int r = 0; r < 4; ++r) {
                int m = m_blk + wm * 64 + mt * 16 + kg * 4 + r;
                float vv = acc[mt][nt][r] + bn;
                if (MODE == 3) {
                    ((float*)outp)[(size_t)m * D_MODEL + n] = vv;
                } else {
                    int b = m >> 11, t = m & 2047, h = n >> 6, dki = n & 63;
                    unsigned short* o = (unsigned short*)outp;
                    if (MODE == 0)
                        o[((size_t)(b * 16 + h) * 2048 + t) * 64 + dki] = f32_to_bf16(vv);
                    else
                        o[((size_t)(b * 16 + h) * 64 + dki) * 2048 + t] = f32_to_bf16(vv);
                }
            }
    }
}

__global__ __launch_bounds__(256) void gemm_qkv(
    const unsigned short* __restrict__ qb, const unsigned short* __restrict__ kb,
    const unsigned short* __restrict__ vb, const unsigned short* __restrict__ Wqb,
    const unsigned short* __restrict__ Wkb, const unsigned short* __restrict__ Wvb,
    const float* __restrict__ bq, const float* __restrict__ bk, const float* __restrict__ bv,
    unsigned short* __restrict__ Qhp, unsigned short* __restrict__ Khp,
    unsigned short* __restrict__ Vtp)
{
    __shared__ __align__(16) unsigned short As[128 * 64];
    __shared__ __align__(16) unsigned short Ws[64 * 64];
    const int z = blockIdx.z;
    const unsigned short* A = (z == 0) ? qb : (z == 1) ? kb : vb;
    const unsigned short* W = (z == 0) ? Wqb : (z == 1) ? Wkb : Wvb;
    const float* bias = (z == 0) ? bq : (z == 1) ? bk : bv;
    if (z < 2)
        gemm_body<0>(A, W, bias, (z == 0) ? (void*)Qhp : (void*)Khp, As, Ws,
                     blockIdx.x, blockIdx.y);
    else
        gemm_body<2>(A, W, bias, (void*)Vtp, As, Ws, blockIdx.x, blockIdx.y);
}

__global__ __launch_bounds__(256) void gemm_out(
    const unsigned short* __restrict__ ab, const unsigned short* __restrict__ Wob,
    const float* __restrict__ bo, float* __restrict__ outp)
{
    __shared__ __align__(16) unsigned short As[128 * 64];
    __shared__ __align__(16) unsigned short Ws[64 * 64];
    gemm_body<3>(ab, Wob, bo, (void*)outp, As, Ws, blockIdx.x, blockIdx.y);
}

// --------------------------- flash attention --------------------------------
// Block = 4 waves, owns q-chunk pair {p, 31-p}; kv streamed once (uniform
// balance). S^T = mfma(Kfrag, Qfrag): lane holds S^T[key=kg*4+r][q=r16].
// exp2 results are packed (explicit register packing) into bf16x8 PV
// A-operands with MFMA-space key order k=kg*8+j -> actual key
// 16*c+kg*4+j (j<4) / 16*(c+1)+kg*4+(j-4) (j>=4); V fragments are built
// from two b64 LDS reads at the same actual-key positions. One 16x16x32
// MFMA per (f, tile-pair). No LDS round-trip, no shuffles in the loop.
__global__ __launch_bounds__(256) void attn_fwd(
    const unsigned short* __restrict__ Qh, const unsigned short* __restrict__ Kh,
    const unsigned short* __restrict__ Vt, const int* __restrict__ mask,
    const int* __restrict__ causal_p, unsigned short* __restrict__ attnout)
{
    __shared__ __align__(16) unsigned short Ks[2][64 * 64];   // [key][dk] swz
    __shared__ __align__(16) unsigned short Vs[2][64 * 64];   // [dk][key] swz

    const int tid = threadIdx.x;
    const int lane = tid & 63, wave = tid >> 6;
    const int p = blockIdx.x, bh = blockIdx.y;
    const int b = bh >> 4, h = bh & 15;
    const int causal = *causal_p;
    const int r16 = lane & 15, kg = lane >> 4;

    const int qcA = p, qcB = 31 - p;
    const int q0A = qcA * 64 + wave * 16;
    const int q0B = qcB * 64 + wave * 16;

    const unsigned short* Qb = Qh + (size_t)bh * T_ * 64;
    const unsigned short* Kb = Kh + (size_t)bh * T_ * 64;
    const unsigned short* Vb = Vt + (size_t)bh * 64 * T_;
    const int* mb = mask + b * T_;

    // Q fragments (B-operand for S^T: lane holds Q[q0+r16][kg*8+j])
    bf16x8 qfA0 = *(const bf16x8*)(Qb + (size_t)(q0A + r16) * 64 + kg * 8);
    bf16x8 qfA1 = *(const bf16x8*)(Qb + (size_t)(q0A + r16) * 64 + 32 + kg * 8);
    bf16x8 qfB0 = *(const bf16x8*)(Qb + (size_t)(q0B + r16) * 64 + kg * 8);
    bf16x8 qfB1 = *(const bf16x8*)(Qb + (size_t)(q0B + r16) * 64 + 32 + kg * 8);

    float lA = 0.f, lB = 0.f;            // per-lane partial for q = r16
    f32x4 oA[4], oB[4];
    #pragma unroll
    for (int f = 0; f < 4; ++f) { oA[f] = (f32x4){0,0,0,0}; oB[f] = (f32x4){0,0,0,0}; }
    const float sc2 = 0.18033688011112042f;   // log2(e) / sqrt(64)
    const int lim = wave * 16 + r16;          // causal limit on diagonal tile

    const int nT = causal ? (qcB + 1) : 32;

    auto stage = [&](int buf, int t) {
        int t0 = t * 64;
        #pragma unroll
        for (int j = 0; j < 2; ++j) {
            int si = j * 256 + tid;
            int row = si >> 3, cg = (si & 7) ^ (row & 7);
            gload_lds16(Kb + (size_t)(t0 + row) * 64 + cg * 8,
                        (char*)Ks[buf] + (j * 256 + wave * 64) * 16);
            gload_lds16(Vb + (size_t)row * T_ + t0 + cg * 8,
                        (char*)Vs[buf] + (j * 256 + wave * 64) * 16);
        }
    };

    stage(0, 0);
    for (int t = 0; t < nT; ++t) {
        __syncthreads();              // stage(t) complete
        if (t + 1 < nT) stage((t + 1) & 1, t + 1);   // prefetch over compute
        const unsigned short* Kst = Ks[t & 1];
        const unsigned short* Vst = Vs[t & 1];
        const int t0 = t * 64;
        const bool activeA = !causal || (t <= qcA);          // block-uniform
        const bool needcA = causal && (t == qcA);
        const bool needcB = causal && (t == qcB);

        // key mask for this 64-key tile as a ballot bitmask
        unsigned long long km = __ballot(mb[t0 + lane] != 0);

        // ---- S^T = K Q^T  (K frags shared between chunks) ----
        f32x4 sA[4], sB[4];
        #pragma unroll
        for (int c = 0; c < 4; ++c) {
            int key = c * 16 + r16;
            bf16x8 kf0 = *(const bf16x8*)(Kst + key * 64 + ((kg ^ (key & 7)) * 8));
            bf16x8 kf1 = *(const bf16x8*)(Kst + key * 64 + (((4 + kg) ^ (key & 7)) * 8));
            f32x4 zB = (f32x4){0,0,0,0};
            zB = MFMA(kf0, qfB0, zB);
            zB = MFMA(kf1, qfB1, zB);
            sB[c] = zB;
            if (activeA) {
                f32x4 zA = (f32x4){0,0,0,0};
                zA = MFMA(kf0, qfA0, zA);
                zA = MFMA(kf1, qfA1, zA);
                sA[c] = zA;
            }
        }

        // ---- exp2 + masks + pack into bf16x8 PV A-operands (tile pairs) ----
        union pk_t { unsigned u[4]; bf16x8 v; };
        pk_t paA[2], paB[2];
        #pragma unroll
        for (int c = 0; c < 4; ++c) {
            unsigned mc = (unsigned)(km >> (c * 16));   // 16 mask bits of tile c
            float pBv[4], pAv[4];
            #pragma unroll
            for (int r = 0; r < 4; ++r) {
                int kbit = kg * 4 + r;                  // key within 16-tile
                bool mk = (mc >> kbit) & 1;
                int kk = c * 16 + kbit;                 // key within 64-tile
                bool okB = mk && (!needcB || (kk <= lim));
                float eB = okB ? __builtin_amdgcn_exp2f(sB[c][r] * sc2) : 0.f;
                pBv[r] = eB; lB += eB;
                if (activeA) {
                    bool okA = mk && (!needcA || (kk <= lim));
                    float eA = okA ? __builtin_amdgcn_exp2f(sA[c][r] * sc2) : 0.f;
                    pAv[r] = eA; lA += eA;
                }
            }
            int half = (c & 1) * 2;                     // u-slot within pair
            paB[c >> 1].u[half]     = f32_to_bf16_fast(pBv[0]) | (f32_to_bf16_fast(pBv[1]) << 16);
            paB[c >> 1].u[half + 1] = f32_to_bf16_fast(pBv[2]) | (f32_to_bf16_fast(pBv[3]) << 16);
            if (activeA) {
                paA[c >> 1].u[half]     = f32_to_bf16_fast(pAv[0]) | (f32_to_bf16_fast(pAv[1]) << 16);
                paA[c >> 1].u[half + 1] = f32_to_bf16_fast(pAv[2]) | (f32_to_bf16_fast(pAv[3]) << 16);
            }
        }

        // ---- O += P V via 16x16x32 over tile pairs (V frags shared) ----
        #pragma unroll
        for (int f = 0; f < 4; ++f) {
            int row = f * 16 + r16;     // dk row in Vs
            int rx = row & 7;
            #pragma unroll
            for (int cp = 0; cp < 2; ++cp) {
                int g0 = (cp * 2) * 2 + (kg >> 1);      // granule: tile 2cp
                int g1 = (cp * 2 + 1) * 2 + (kg >> 1);  // granule: tile 2cp+1
                union { bf16x4 h[2]; bf16x8 v; } vf;
                vf.h[0] = *(const bf16x4*)(Vst + row * 64 + ((g0 ^ rx) * 8) + (kg & 1) * 4);
                vf.h[1] = *(const bf16x4*)(Vst + row * 64 + ((g1 ^ rx) * 8) + (kg & 1) * 4);
                oB[f] = MFMA(paB[cp].v, vf.v, oB[f]);
                if (activeA) oA[f] = MFMA(paA[cp].v, vf.v, oA[f]);
            }
        }
    }

    // ---- epilogue: reduce l across kg groups, normalize, store [B,T,D] ----
    lA += __shfl_xor(lA, 16, 64); lA += __shfl_xor(lA, 32, 64);
    lB += __shfl_xor(lB, 16, 64); lB += __shfl_xor(lB, 32, 64);
    float invA = (lA > 0.f) ? 1.0f / lA : 0.f;   // every lane: inv for q=r16
    float invB = (lB > 0.f) ? 1.0f / lB : 0.f;
    #pragma unroll
    for (int r = 0; r < 4; ++r) {
        int ql = kg * 4 + r;                      // local q row to store
        float iA = __shfl(invA, ql, 64);
        float iB = __shfl(invB, ql, 64);
        size_t baseA = ((size_t)(b * T_ + q0A + ql)) * D_MODEL + h * 64;
        size_t baseB = ((size_t)(b * T_ + q0B + ql)) * D_MODEL + h * 64;
        #pragma unroll
        for (int f = 0; f < 4; ++f) {
            attnout[baseA + f * 16 + r16] = f32_to_bf16(oA[f][r] * iA);
            attnout[baseB + f * 16 + r16] = f32_to_bf16(oB[f][r] * iB);
        }
    }
}

// --------------------------- launch -----------------------------------------
extern "C" void kernel_launch(void* const* d_in, const int* in_sizes, int n_in,
                              void* d_out, int out_size, void* d_ws, size_t ws_size,
                              hipStream_t stream) {
    const float* q  = (const float*)d_in[0];
    const float* k  = (const float*)d_in[1];
    const float* v  = (const float*)d_in[2];
    const float* Wq = (const float*)d_in[3];
    const float* bq = (const float*)d_in[4];
    const float* Wk = (const float*)d_in[5];
    const float* bk = (const float*)d_in[6];
    const float* Wv = (const float*)d_in[7];
    const float* bv = (const float*)d_in[8];
    const float* Wo = (const float*)d_in[9];
    const float* bo = (const float*)d_in[10];
    const int* mask   = (const int*)d_in[11];
    const int* causal = (const int*)d_in[12];

    const size_t SZ_TOK = (size_t)M_TOK * D_MODEL;   // 4M elems
    const size_t SZ_W   = (size_t)D_MODEL * D_MODEL; // 1M elems

    unsigned short* qb  = (unsigned short*)d_ws;
    unsigned short* kb  = qb  + SZ_TOK;
    unsigned short* vb  = kb  + SZ_TOK;
    unsigned short* Wqb = vb  + SZ_TOK;
    unsigned short* Wkb = Wqb + SZ_W;
    unsigned short* Wvb = Wkb + SZ_W;
    unsigned short* Wob = Wvb + SZ_W;
    unsigned short* Qhp = Wob + SZ_W;
    unsigned short* Khp = Qhp + SZ_TOK;
    unsigned short* Vtp = Khp + SZ_TOK;
    unsigned short* ab  = Vtp + SZ_TOK;              // 64 MB total

    cvt_all<<<16384, 256, 0, stream>>>(q, k, v, Wq, Wk, Wv, Wo, (ushort4*)qb);

    gemm_qkv<<<dim3(D_MODEL / 64, M_TOK / 128, 3), 256, 0, stream>>>(
        qb, kb, vb, Wqb, Wkb, Wvb, bq, bk, bv, Qhp, Khp, Vtp);

    attn_fwd<<<dim3(16, 32), 256, 0, stream>>>(Qhp, Khp, Vtp, mask, causal, ab);

    gemm_out<<<dim3(D_MODEL / 64, M_TOK / 128), 256, 0, stream>>>(ab, Wob, bo,
                                                                  (float*)d_out);
}

// Round 6
// 233.013 us; speedup vs baseline: 1.1965x; 1.0704x over previous
//
#include <hip/hip_runtime.h>
#include <cstdint>
#include <cstddef>

// ---------------------------------------------------------------------------
// MHA: out = softmax(causal(mask((XWq)(XWk)^T/8))) (XWv) Wo + biases
// B=2, T=2048, D=1024, H=16, dk=64. bf16 MFMA, fp32 accumulate.
// R6: (1) attention un-paired: 1024 blocks (one 64-q chunk each), per-CU
//     work balanced via qc quadruple map {y0,15-y0,16+y0,31-y0}; bh in
//     blockIdx.x for XCD KV L2 locality. (2) GEMM epilogues packed: operand-
//     swapped MFMA (C^T) gives lanes n-consecutive quads -> ushort4/float4
//     stores for Q/K/out; V unswapped -> m-consecutive ushort4. Q/K now plain
//     row-major [B,T,H*dk].
// ---------------------------------------------------------------------------

typedef __bf16 bf16x8 __attribute__((ext_vector_type(8)));
typedef __bf16 bf16x4 __attribute__((ext_vector_type(4)));
typedef float f32x4 __attribute__((ext_vector_type(4)));

#define MFMA(a, b, c) __builtin_amdgcn_mfma_f32_16x16x32_bf16((a), (b), (c), 0, 0, 0)

static constexpr int D_MODEL = 1024;
static constexpr int T_ = 2048;
static constexpr int M_TOK = 4096;   // B*T

__device__ __forceinline__ unsigned short f32_to_bf16(float f) {   // RNE
    union { float f; uint32_t u; } v; v.f = f;
    uint32_t u = v.u;
    uint32_t r = u + 0x7fffu + ((u >> 16) & 1u);
    return (unsigned short)(r >> 16);
}
__device__ __forceinline__ unsigned f32_to_bf16_fast(float f) {    // half-up
    union { float f; uint32_t u; } v; v.f = f;
    return (v.u + 0x8000u) >> 16;
}

typedef __attribute__((address_space(1))) void* as1_ptr;
typedef __attribute__((address_space(3))) void* as3_ptr;
__device__ __forceinline__ void gload_lds16(const void* g, void* l) {
    // lane's 16B land at (wave-uniform l) + lane*16
    __builtin_amdgcn_global_load_lds((as1_ptr)(void*)g, (as3_ptr)l, 16, 0, 0);
}

// --------------------------- fused fp32 -> bf16 convert ---------------------
// dst (float4 units): q[0,1M) k[1M,2M) v[2M,3M) Wq Wk Wv Wo [3M..4M)
__global__ __launch_bounds__(256) void cvt_all(
    const float* __restrict__ q, const float* __restrict__ k,
    const float* __restrict__ v, const float* __restrict__ wq,
    const float* __restrict__ wk, const float* __restrict__ wv,
    const float* __restrict__ wo, ushort4* __restrict__ dst) {
    int i = blockIdx.x * blockDim.x + threadIdx.x;
    constexpr int R = 1 << 20;        // 1M float4 per token tensor
    const float* s;
    int idx;
    if (i < 3 * R) {
        s = (i < R) ? q : (i < 2 * R) ? k : v;
        idx = i & (R - 1);
    } else {
        int j = i - 3 * R;
        int w = j >> 18;
        s = (w == 0) ? wq : (w == 1) ? wk : (w == 2) ? wv : wo;
        idx = j & ((1 << 18) - 1);
    }
    float4 f = ((const float4*)s)[idx];
    ushort4 o;
    o.x = (unsigned short)f32_to_bf16(f.x); o.y = (unsigned short)f32_to_bf16(f.y);
    o.z = (unsigned short)f32_to_bf16(f.z); o.w = (unsigned short)f32_to_bf16(f.w);
    dst[i] = o;
}

// --------------------------- GEMM: C = A @ W^T + bias -----------------------
// Tile 128x64, BK=64, 4 waves 2x2, wave = 64x32, global_load_lds(16B), XOR
// swizzle. MODE 0: bf16 row-major [M][1024] (Q,K; SWAPPED epilogue — lane
// holds 4 n-consecutive vals -> ushort4 store). MODE 2: bf16 [B][H][64][T]
// (V; UNswapped — lane holds 4 m-consecutive vals -> ushort4 store).
// MODE 3: f32 row-major [M][1024] (SWAPPED -> float4 store).
template<int MODE>
__device__ __forceinline__ void gemm_body(
    const unsigned short* __restrict__ A, const unsigned short* __restrict__ W,
    const float* __restrict__ bias, void* __restrict__ outp,
    unsigned short* As, unsigned short* Ws, int bx, int by)
{
    constexpr bool SWAP = (MODE != 2);
    const int tid = threadIdx.x;
    const int lane = tid & 63, wave = tid >> 6;
    const int wm = wave >> 1, wn = wave & 1;
    const int r16 = lane & 15, kg = lane >> 4;
    const int m_blk = by * 128, n_blk = bx * 64;

    f32x4 acc[4][2];
    #pragma unroll
    for (int mt = 0; mt < 4; ++mt)
        #pragma unroll
        for (int nt = 0; nt < 2; ++nt) acc[mt][nt] = (f32x4){0, 0, 0, 0};

    for (int k0 = 0; k0 < D_MODEL; k0 += 64) {
        __syncthreads();
        #pragma unroll
        for (int j = 0; j < 4; ++j) {           // A tile: 128x64 = 16 KB
            int si = j * 256 + tid;
            int row = si >> 3, cg = (si & 7) ^ (row & 7);
            gload_lds16(A + (size_t)(m_blk + row) * D_MODEL + k0 + cg * 8,
                        (char*)As + (j * 256 + wave * 64) * 16);
        }
        #pragma unroll
        for (int j = 0; j < 2; ++j) {           // W tile: 64x64 = 8 KB
            int si = j * 256 + tid;
            int row = si >> 3, cg = (si & 7) ^ (row & 7);
            gload_lds16(W + (size_t)(n_blk + row) * D_MODEL + k0 + cg * 8,
                        (char*)Ws + (j * 256 + wave * 64) * 16);
        }
        __syncthreads();                        // drains vmcnt
        #pragma unroll
        for (int kc = 0; kc < 2; ++kc) {
            bf16x8 af[4], wf[2];
            #pragma unroll
            for (int mt = 0; mt < 4; ++mt) {
                int row = wm * 64 + mt * 16 + r16;
                af[mt] = *(const bf16x8*)(As + row * 64 + (((kc * 4 + kg) ^ (row & 7)) * 8));
            }
            #pragma unroll
            for (int nt = 0; nt < 2; ++nt) {
                int row = wn * 32 + nt * 16 + r16;
                wf[nt] = *(const bf16x8*)(Ws + row * 64 + (((kc * 4 + kg) ^ (row & 7)) * 8));
            }
            #pragma unroll
            for (int mt = 0; mt < 4; ++mt)
                #pragma unroll
                for (int nt = 0; nt < 2; ++nt)
                    acc[mt][nt] = SWAP ? MFMA(wf[nt], af[mt], acc[mt][nt])
                                       : MFMA(af[mt], wf[nt], acc[mt][nt]);
        }
    }
    if (MODE == 2) {
        // UNswapped C/D: lane holds m = kg*4+r (consecutive), n = r16 fixed.
        #pragma unroll
        for (int nt = 0; nt < 2; ++nt) {
            int n = n_blk + wn * 32 + nt * 16 + r16;
            float bn = bias[n];
            int hh = n >> 6, dki = n & 63;
            #pragma unroll
            for (int mt = 0; mt < 4; ++mt) {
                int m0 = m_blk + wm * 64 + mt * 16 + kg * 4;
                int bb = m0 >> 11, ti = m0 & 2047;
                ushort4 pk;
                pk.x = f32_to_bf16(acc[mt][nt][0] + bn);
                pk.y = f32_to_bf16(acc[mt][nt][1] + bn);
                pk.z = f32_to_bf16(acc[mt][nt][2] + bn);
                pk.w = f32_to_bf16(acc[mt][nt][3] + bn);
                *(ushort4*)((unsigned short*)outp +
                    ((size_t)(bb * 16 + hh) * 64 + dki) * 2048 + ti) = pk;
            }
        }
    } else {
        // SWAPPED C/D: lane holds n = kg*4+r (consecutive), m = r16 fixed.
        #pragma unroll
        for (int nt = 0; nt < 2; ++nt) {
            int n0 = n_blk + wn * 32 + nt * 16 + kg * 4;
            float4 bn4 = *(const float4*)(bias + n0);
            #pragma unroll
            for (int mt = 0; mt < 4; ++mt) {
                int m = m_blk + wm * 64 + mt * 16 + r16;
                if (MODE == 3) {
                    float4 st;
                    st.x = acc[mt][nt][0] + bn4.x; st.y = acc[mt][nt][1] + bn4.y;
                    st.z = acc[mt][nt][2] + bn4.z; st.w = acc[mt][nt][3] + bn4.w;
                    *(float4*)((float*)outp + (size_t)m * D_MODEL + n0) = st;
                } else {
                    ushort4 pk;
                    pk.x = f32_to_bf16(acc[mt][nt][0] + bn4.x);
                    pk.y = f32_to_bf16(acc[mt][nt][1] + bn4.y);
                    pk.z = f32_to_bf16(acc[mt][nt][2] + bn4.z);
                    pk.w = f32_to_bf16(acc[mt][nt][3] + bn4.w);
                    *(ushort4*)((unsigned short*)outp + (size_t)m * D_MODEL + n0) = pk;
                }
            }
        }
    }
}

__global__ __launch_bounds__(256) void gemm_qkv(
    const unsigned short* __restrict__ qb, const unsigned short* __restrict__ kb,
    const unsigned short* __restrict__ vb, const unsigned short* __restrict__ Wqb,
    const unsigned short* __restrict__ Wkb, const unsigned short* __restrict__ Wvb,
    const float* __restrict__ bq, const float* __restrict__ bk, const float* __restrict__ bv,
    unsigned short* __restrict__ Qhp, unsigned short* __restrict__ Khp,
    unsigned short* __restrict__ Vtp)
{
    __shared__ __align__(16) unsigned short As[128 * 64];
    __shared__ __align__(16) unsigned short Ws[64 * 64];
    const int z = blockIdx.z;
    const unsigned short* A = (z == 0) ? qb : (z == 1) ? kb : vb;
    const unsigned short* W = (z == 0) ? Wqb : (z == 1) ? Wkb : Wvb;
    const float* bias = (z == 0) ? bq : (z == 1) ? bk : bv;
    if (z < 2)
        gemm_body<0>(A, W, bias, (z == 0) ? (void*)Qhp : (void*)Khp, As, Ws,
                     blockIdx.x, blockIdx.y);
    else
        gemm_body<2>(A, W, bias, (void*)Vtp, As, Ws, blockIdx.x, blockIdx.y);
}

__global__ __launch_bounds__(256) void gemm_out(
    const unsigned short* __restrict__ ab, const unsigned short* __restrict__ Wob,
    const float* __restrict__ bo, float* __restrict__ outp)
{
    __shared__ __align__(16) unsigned short As[128 * 64];
    __shared__ __align__(16) unsigned short Ws[64 * 64];
    gemm_body<3>(ab, Wob, bo, (void*)outp, As, Ws, blockIdx.x, blockIdx.y);
}

// --------------------------- flash attention --------------------------------
// One 64-q chunk per block (4 waves x 16 q). Grid (bh=32, y=32); qc from the
// quadruple map {y0, 15-y0, 16+y0, 31-y0} so every CU's stride-256 block set
// has equal causal work; bh fastest-varying -> 4 distinct heads per XCD (KV
// ~4MB = L2). Register-resident P (R5 scheme): S^T = mfma(Kfrag, Qfrag),
// exp2 packed straight into PV A-operands. Q/K read from row-major
// [B,T,H*dk]; V from [B,H,64,T]. Double-buffered KV staging.
__global__ __launch_bounds__(256) void attn_fwd(
    const unsigned short* __restrict__ Qh, const unsigned short* __restrict__ Kh,
    const unsigned short* __restrict__ Vt, const int* __restrict__ mask,
    const int* __restrict__ causal_p, unsigned short* __restrict__ attnout)
{
    __shared__ __align__(16) unsigned short Ks[2][64 * 64];   // [key][dk] swz
    __shared__ __align__(16) unsigned short Vs[2][64 * 64];   // [dk][key] swz

    const int tid = threadIdx.x;
    const int lane = tid & 63, wave = tid >> 6;
    const int bh = blockIdx.x;
    const int y = blockIdx.y, y0 = y & 7, j4 = y >> 3;
    const int qc = (j4 == 0) ? y0 : (j4 == 1) ? (15 - y0)
                 : (j4 == 2) ? (16 + y0) : (31 - y0);
    const int b = bh >> 4, h = bh & 15;
    const int causal = *causal_p;
    const int r16 = lane & 15, kg = lane >> 4;

    const int q0 = qc * 64 + wave * 16;

    const unsigned short* Qb = Qh + (size_t)b * T_ * D_MODEL + h * 64;
    const unsigned short* Kb = Kh + (size_t)b * T_ * D_MODEL + h * 64;
    const unsigned short* Vb = Vt + (size_t)bh * 64 * T_;
    const int* mb = mask + b * T_;

    // Q fragments (B-operand for S^T: lane holds Q[q0+r16][kg*8+j])
    bf16x8 qf0 = *(const bf16x8*)(Qb + (size_t)(q0 + r16) * D_MODEL + kg * 8);
    bf16x8 qf1 = *(const bf16x8*)(Qb + (size_t)(q0 + r16) * D_MODEL + 32 + kg * 8);

    float l = 0.f;                       // per-lane partial for q = r16
    f32x4 o[4];
    #pragma unroll
    for (int f = 0; f < 4; ++f) o[f] = (f32x4){0, 0, 0, 0};
    const float sc2 = 0.18033688011112042f;   // log2(e) / sqrt(64)
    const int lim = wave * 16 + r16;          // causal limit on diagonal tile

    const int nT = causal ? (qc + 1) : 32;

    auto stage = [&](int buf, int t) {
        int t0 = t * 64;
        #pragma unroll
        for (int j = 0; j < 2; ++j) {
            int si = j * 256 + tid;
            int row = si >> 3, cg = (si & 7) ^ (row & 7);
            gload_lds16(Kb + (size_t)(t0 + row) * D_MODEL + cg * 8,
                        (char*)Ks[buf] + (j * 256 + wave * 64) * 16);
            gload_lds16(Vb + (size_t)row * T_ + t0 + cg * 8,
                        (char*)Vs[buf] + (j * 256 + wave * 64) * 16);
        }
    };

    stage(0, 0);
    for (int t = 0; t < nT; ++t) {
        __syncthreads();              // stage(t) complete
        if (t + 1 < nT) stage((t + 1) & 1, t + 1);   // prefetch over compute
        const unsigned short* Kst = Ks[t & 1];
        const unsigned short* Vst = Vs[t & 1];
        const int t0 = t * 64;
        const bool needc = causal && (t == qc);

        // key mask for this 64-key tile as a ballot bitmask
        unsigned long long km = __ballot(mb[t0 + lane] != 0);

        // ---- S^T = K Q^T ----
        f32x4 s[4];
        #pragma unroll
        for (int c = 0; c < 4; ++c) {
            int key = c * 16 + r16;
            bf16x8 kf0 = *(const bf16x8*)(Kst + key * 64 + ((kg ^ (key & 7)) * 8));
            bf16x8 kf1 = *(const bf16x8*)(Kst + key * 64 + (((4 + kg) ^ (key & 7)) * 8));
            f32x4 z = (f32x4){0, 0, 0, 0};
            z = MFMA(kf0, qf0, z);
            z = MFMA(kf1, qf1, z);
            s[c] = z;
        }

        // ---- exp2 + masks + pack into bf16x8 PV A-operands (tile pairs) ----
        union pk_t { unsigned u[4]; bf16x8 v; };
        pk_t pa[2];
        #pragma unroll
        for (int c = 0; c < 4; ++c) {
            unsigned mc = (unsigned)(km >> (c * 16));   // 16 mask bits of tile c
            float pv[4];
            #pragma unroll
            for (int r = 0; r < 4; ++r) {
                int kbit = kg * 4 + r;                  // key within 16-tile
                bool mk = (mc >> kbit) & 1;
                int kk = c * 16 + kbit;                 // key within 64-tile
                bool ok = mk && (!needc || (kk <= lim));
                float e = ok ? __builtin_amdgcn_exp2f(s[c][r] * sc2) : 0.f;
                pv[r] = e; l += e;
            }
            int half = (c & 1) * 2;                     // u-slot within pair
            pa[c >> 1].u[half]     = f32_to_bf16_fast(pv[0]) | (f32_to_bf16_fast(pv[1]) << 16);
            pa[c >> 1].u[half + 1] = f32_to_bf16_fast(pv[2]) | (f32_to_bf16_fast(pv[3]) << 16);
        }

        // ---- O += P V via 16x16x32 over tile pairs ----
        #pragma unroll
        for (int f = 0; f < 4; ++f) {
            int row = f * 16 + r16;     // dk row in Vs
            int rx = row & 7;
            #pragma unroll
            for (int cp = 0; cp < 2; ++cp) {
                int g0 = (cp * 2) * 2 + (kg >> 1);      // granule: tile 2cp
                int g1 = (cp * 2 + 1) * 2 + (kg >> 1);  // granule: tile 2cp+1
                union { bf16x4 h[2]; bf16x8 v; } vf;
                vf.h[0] = *(const bf16x4*)(Vst + row * 64 + ((g0 ^ rx) * 8) + (kg & 1) * 4);
                vf.h[1] = *(const bf16x4*)(Vst + row * 64 + ((g1 ^ rx) * 8) + (kg & 1) * 4);
                o[f] = MFMA(pa[cp].v, vf.v, o[f]);
            }
        }
    }

    // ---- epilogue: reduce l across kg groups, normalize, store [B,T,D] ----
    l += __shfl_xor(l, 16, 64); l += __shfl_xor(l, 32, 64);
    float inv = (l > 0.f) ? 1.0f / l : 0.f;   // every lane: inv for q=r16
    #pragma unroll
    for (int r = 0; r < 4; ++r) {
        int ql = kg * 4 + r;                  // local q row to store
        float iv = __shfl(inv, ql, 64);
        size_t base = ((size_t)(b * T_ + q0 + ql)) * D_MODEL + h * 64;
        #pragma unroll
        for (int f = 0; f < 4; ++f)
            attnout[base + f * 16 + r16] = f32_to_bf16(o[f][r] * iv);
    }
}

// --------------------------- launch -----------------------------------------
extern "C" void kernel_launch(void* const* d_in, const int* in_sizes, int n_in,
                              void* d_out, int out_size, void* d_ws, size_t ws_size,
                              hipStream_t stream) {
    const float* q  = (const float*)d_in[0];
    const float* k  = (const float*)d_in[1];
    const float* v  = (const float*)d_in[2];
    const float* Wq = (const float*)d_in[3];
    const float* bq = (const float*)d_in[4];
    const float* Wk = (const float*)d_in[5];
    const float* bk = (const float*)d_in[6];
    const float* Wv = (const float*)d_in[7];
    const float* bv = (const float*)d_in[8];
    const float* Wo = (const float*)d_in[9];
    const float* bo = (const float*)d_in[10];
    const int* mask   = (const int*)d_in[11];
    const int* causal = (const int*)d_in[12];

    const size_t SZ_TOK = (size_t)M_TOK * D_MODEL;   // 4M elems
    const size_t SZ_W   = (size_t)D_MODEL * D_MODEL; // 1M elems

    unsigned short* qb  = (unsigned short*)d_ws;
    unsigned short* kb  = qb  + SZ_TOK;
    unsigned short* vb  = kb  + SZ_TOK;
    unsigned short* Wqb = vb  + SZ_TOK;
    unsigned short* Wkb = Wqb + SZ_W;
    unsigned short* Wvb = Wkb + SZ_W;
    unsigned short* Wob = Wvb + SZ_W;
    unsigned short* Qhp = Wob + SZ_W;
    unsigned short* Khp = Qhp + SZ_TOK;
    unsigned short* Vtp = Khp + SZ_TOK;
    unsigned short* ab  = Vtp + SZ_TOK;              // 64 MB total

    cvt_all<<<16384, 256, 0, stream>>>(q, k, v, Wq, Wk, Wv, Wo, (ushort4*)qb);

    gemm_qkv<<<dim3(D_MODEL / 64, M_TOK / 128, 3), 256, 0, stream>>>(
        qb, kb, vb, Wqb, Wkb, Wvb, bq, bk, bv, Qhp, Khp, Vtp);

    attn_fwd<<<dim3(32, 32), 256, 0, stream>>>(Qhp, Khp, Vtp, mask, causal, ab);

    gemm_out<<<dim3(D_MODEL / 64, M_TOK / 128), 256, 0, stream>>>(ab, Wob, bo,
                                                                  (float*)d_out);
}

// Round 7
// 225.073 us; speedup vs baseline: 1.2387x; 1.0353x over previous
//
#include <hip/hip_runtime.h>
#include <cstdint>
#include <cstddef>

// ---------------------------------------------------------------------------
// MHA: out = softmax(causal(mask((XWq)(XWk)^T/8))) (XWv) Wo + biases
// B=2, T=2048, D=1024, H=16, dk=64. bf16 MFMA, fp32 accumulate.
// R7: (1) V stored with sigma-permuted key order (sigma = P-pack's MFMA key
//     map) -> attention V-frags become single b128 reads (kills the 4.3M
//     bank-conflict cycles of R6's b64 pairs). (2) Hot loop VALU cut:
//     wave-uniform all-ones-mask fast path + causal handled only on the
//     diagonal tile. (3) gemm_qkv -> 128x128 tile (3 blocks/CU) with packed
//     epilogues; gemm_out stays 128x64.
// ---------------------------------------------------------------------------

typedef __bf16 bf16x8 __attribute__((ext_vector_type(8)));
typedef float f32x4 __attribute__((ext_vector_type(4)));

#define MFMA(a, b, c) __builtin_amdgcn_mfma_f32_16x16x32_bf16((a), (b), (c), 0, 0, 0)

static constexpr int D_MODEL = 1024;
static constexpr int T_ = 2048;
static constexpr int M_TOK = 4096;   // B*T

__device__ __forceinline__ unsigned short f32_to_bf16(float f) {   // RNE
    union { float f; uint32_t u; } v; v.f = f;
    uint32_t u = v.u;
    uint32_t r = u + 0x7fffu + ((u >> 16) & 1u);
    return (unsigned short)(r >> 16);
}
__device__ __forceinline__ unsigned f32_to_bf16_fast(float f) {    // half-up
    union { float f; uint32_t u; } v; v.f = f;
    return (v.u + 0x8000u) >> 16;
}

typedef __attribute__((address_space(1))) void* as1_ptr;
typedef __attribute__((address_space(3))) void* as3_ptr;
__device__ __forceinline__ void gload_lds16(const void* g, void* l) {
    // lane's 16B land at (wave-uniform l) + lane*16
    __builtin_amdgcn_global_load_lds((as1_ptr)(void*)g, (as3_ptr)l, 16, 0, 0);
}

// sigma: actual key (within 64) -> storage index matching PV MFMA k-slots.
__device__ __forceinline__ int keyperm(int k) {
    return (k & 32) | ((k & 12) << 1) | ((k & 16) >> 2) | (k & 3);
}

// --------------------------- fused fp32 -> bf16 convert ---------------------
// dst (float4 units): q[0,1M) k[1M,2M) v[2M,3M) Wq Wk Wv Wo [3M..4M)
__global__ __launch_bounds__(256) void cvt_all(
    const float* __restrict__ q, const float* __restrict__ k,
    const float* __restrict__ v, const float* __restrict__ wq,
    const float* __restrict__ wk, const float* __restrict__ wv,
    const float* __restrict__ wo, ushort4* __restrict__ dst) {
    int i = blockIdx.x * blockDim.x + threadIdx.x;
    constexpr int R = 1 << 20;        // 1M float4 per token tensor
    const float* s;
    int idx;
    if (i < 3 * R) {
        s = (i < R) ? q : (i < 2 * R) ? k : v;
        idx = i & (R - 1);
    } else {
        int j = i - 3 * R;
        int w = j >> 18;
        s = (w == 0) ? wq : (w == 1) ? wk : (w == 2) ? wv : wo;
        idx = j & ((1 << 18) - 1);
    }
    float4 f = ((const float4*)s)[idx];
    ushort4 o;
    o.x = (unsigned short)f32_to_bf16(f.x); o.y = (unsigned short)f32_to_bf16(f.y);
    o.z = (unsigned short)f32_to_bf16(f.z); o.w = (unsigned short)f32_to_bf16(f.w);
    dst[i] = o;
}

// --------------------------- GEMM: C = A @ W^T + bias -----------------------
// Tile 128 x (NT16*32), BK=64, 4 waves 2x2, global_load_lds(16B), XOR swizzle.
// MODE 0: bf16 row-major [M][1024] (Q,K; SWAPPED epilogue -> ushort4 stores).
// MODE 2: bf16 [B][H][64][Tperm] (V; UNswapped, t sigma-permuted per 64-blk).
// MODE 3: f32 row-major [M][1024] (SWAPPED -> float4 stores).
template<int MODE, int NT16>
__device__ __forceinline__ void gemm_body(
    const unsigned short* __restrict__ A, const unsigned short* __restrict__ W,
    const float* __restrict__ bias, void* __restrict__ outp,
    unsigned short* As, unsigned short* Ws, int bx, int by)
{
    constexpr bool SWAP = (MODE != 2);
    const int tid = threadIdx.x;
    const int lane = tid & 63, wave = tid >> 6;
    const int wm = wave >> 1, wn = wave & 1;
    const int r16 = lane & 15, kg = lane >> 4;
    const int m_blk = by * 128, n_blk = bx * (NT16 * 32);

    f32x4 acc[4][NT16];
    #pragma unroll
    for (int mt = 0; mt < 4; ++mt)
        #pragma unroll
        for (int nt = 0; nt < NT16; ++nt) acc[mt][nt] = (f32x4){0, 0, 0, 0};

    for (int k0 = 0; k0 < D_MODEL; k0 += 64) {
        __syncthreads();
        #pragma unroll
        for (int j = 0; j < 4; ++j) {           // A tile: 128x64 = 16 KB
            int si = j * 256 + tid;
            int row = si >> 3, cg = (si & 7) ^ (row & 7);
            gload_lds16(A + (size_t)(m_blk + row) * D_MODEL + k0 + cg * 8,
                        (char*)As + (j * 256 + wave * 64) * 16);
        }
        #pragma unroll
        for (int j = 0; j < NT16; ++j) {        // W tile: (NT16*32)x64
            int si = j * 256 + tid;
            int row = si >> 3, cg = (si & 7) ^ (row & 7);
            gload_lds16(W + (size_t)(n_blk + row) * D_MODEL + k0 + cg * 8,
                        (char*)Ws + (j * 256 + wave * 64) * 16);
        }
        __syncthreads();                        // drains vmcnt
        #pragma unroll
        for (int kc = 0; kc < 2; ++kc) {
            bf16x8 af[4], wf[NT16];
            #pragma unroll
            for (int mt = 0; mt < 4; ++mt) {
                int row = wm * 64 + mt * 16 + r16;
                af[mt] = *(const bf16x8*)(As + row * 64 + (((kc * 4 + kg) ^ (row & 7)) * 8));
            }
            #pragma unroll
            for (int nt = 0; nt < NT16; ++nt) {
                int row = wn * (NT16 * 16) + nt * 16 + r16;
                wf[nt] = *(const bf16x8*)(Ws + row * 64 + (((kc * 4 + kg) ^ (row & 7)) * 8));
            }
            #pragma unroll
            for (int mt = 0; mt < 4; ++mt)
                #pragma unroll
                for (int nt = 0; nt < NT16; ++nt)
                    acc[mt][nt] = SWAP ? MFMA(wf[nt], af[mt], acc[mt][nt])
                                       : MFMA(af[mt], wf[nt], acc[mt][nt]);
        }
    }
    if (MODE == 2) {
        // UNswapped C/D: lane holds m = kg*4+r (t, consecutive), n = r16 fixed.
        #pragma unroll
        for (int nt = 0; nt < NT16; ++nt) {
            int n = n_blk + wn * (NT16 * 16) + nt * 16 + r16;
            float bn = bias[n];
            int hh = n >> 6, dki = n & 63;
            #pragma unroll
            for (int mt = 0; mt < 4; ++mt) {
                int m0 = m_blk + wm * 64 + mt * 16 + kg * 4;
                int mp = (m0 & ~63) | keyperm(m0 & 63);   // sigma within 64-blk
                int bb = mp >> 11, ti = mp & 2047;
                ushort4 pk;
                pk.x = f32_to_bf16(acc[mt][nt][0] + bn);
                pk.y = f32_to_bf16(acc[mt][nt][1] + bn);
                pk.z = f32_to_bf16(acc[mt][nt][2] + bn);
                pk.w = f32_to_bf16(acc[mt][nt][3] + bn);
                *(ushort4*)((unsigned short*)outp +
                    ((size_t)(bb * 16 + hh) * 64 + dki) * 2048 + ti) = pk;
            }
        }
    } else {
        // SWAPPED C/D: lane holds n = kg*4+r (consecutive), m = r16 fixed.
        #pragma unroll
        for (int nt = 0; nt < NT16; ++nt) {
            int n0 = n_blk + wn * (NT16 * 16) + nt * 16 + kg * 4;
            float4 bn4 = *(const float4*)(bias + n0);
            #pragma unroll
            for (int mt = 0; mt < 4; ++mt) {
                int m = m_blk + wm * 64 + mt * 16 + r16;
                if (MODE == 3) {
                    float4 st;
                    st.x = acc[mt][nt][0] + bn4.x; st.y = acc[mt][nt][1] + bn4.y;
                    st.z = acc[mt][nt][2] + bn4.z; st.w = acc[mt][nt][3] + bn4.w;
                    *(float4*)((float*)outp + (size_t)m * D_MODEL + n0) = st;
                } else {
                    ushort4 pk;
                    pk.x = f32_to_bf16(acc[mt][nt][0] + bn4.x);
                    pk.y = f32_to_bf16(acc[mt][nt][1] + bn4.y);
                    pk.z = f32_to_bf16(acc[mt][nt][2] + bn4.z);
                    pk.w = f32_to_bf16(acc[mt][nt][3] + bn4.w);
                    *(ushort4*)((unsigned short*)outp + (size_t)m * D_MODEL + n0) = pk;
                }
            }
        }
    }
}

__global__ __launch_bounds__(256) void gemm_qkv(
    const unsigned short* __restrict__ qb, const unsigned short* __restrict__ kb,
    const unsigned short* __restrict__ vb, const unsigned short* __restrict__ Wqb,
    const unsigned short* __restrict__ Wkb, const unsigned short* __restrict__ Wvb,
    const float* __restrict__ bq, const float* __restrict__ bk, const float* __restrict__ bv,
    unsigned short* __restrict__ Qhp, unsigned short* __restrict__ Khp,
    unsigned short* __restrict__ Vtp)
{
    __shared__ __align__(16) unsigned short As[128 * 64];
    __shared__ __align__(16) unsigned short Ws[128 * 64];
    const int z = blockIdx.z;
    const unsigned short* A = (z == 0) ? qb : (z == 1) ? kb : vb;
    const unsigned short* W = (z == 0) ? Wqb : (z == 1) ? Wkb : Wvb;
    const float* bias = (z == 0) ? bq : (z == 1) ? bk : bv;
    if (z < 2)
        gemm_body<0, 4>(A, W, bias, (z == 0) ? (void*)Qhp : (void*)Khp, As, Ws,
                        blockIdx.x, blockIdx.y);
    else
        gemm_body<2, 4>(A, W, bias, (void*)Vtp, As, Ws, blockIdx.x, blockIdx.y);
}

__global__ __launch_bounds__(256) void gemm_out(
    const unsigned short* __restrict__ ab, const unsigned short* __restrict__ Wob,
    const float* __restrict__ bo, float* __restrict__ outp)
{
    __shared__ __align__(16) unsigned short As[128 * 64];
    __shared__ __align__(16) unsigned short Ws[64 * 64];
    gemm_body<3, 2>(ab, Wob, bo, (void*)outp, As, Ws, blockIdx.x, blockIdx.y);
}

// --------------------------- flash attention --------------------------------
// One 64-q chunk per block (4 waves x 16 q); qc quadruple map balances causal
// work per CU; bh fastest-varying for XCD KV L2 locality. Register-resident P
// (S^T = mfma(K,Q)); V stored key-permuted so PV B-frags are single b128
// reads. Hot loop: all-ones-mask fast path (uniform branch), causal only on
// the diagonal tile.
__global__ __launch_bounds__(256) void attn_fwd(
    const unsigned short* __restrict__ Qh, const unsigned short* __restrict__ Kh,
    const unsigned short* __restrict__ Vt, const int* __restrict__ mask,
    const int* __restrict__ causal_p, unsigned short* __restrict__ attnout)
{
    __shared__ __align__(16) unsigned short Ks[2][64 * 64];   // [key][dk] swz
    __shared__ __align__(16) unsigned short Vs[2][64 * 64];   // [dk][kperm] swz

    const int tid = threadIdx.x;
    const int lane = tid & 63, wave = tid >> 6;
    const int bh = blockIdx.x;
    const int y = blockIdx.y, y0 = y & 7, j4 = y >> 3;
    const int qc = (j4 == 0) ? y0 : (j4 == 1) ? (15 - y0)
                 : (j4 == 2) ? (16 + y0) : (31 - y0);
    const int b = bh >> 4, h = bh & 15;
    const int causal = *causal_p;
    const int r16 = lane & 15, kg = lane >> 4;

    const int q0 = qc * 64 + wave * 16;

    const unsigned short* Qb = Qh + (size_t)b * T_ * D_MODEL + h * 64;
    const unsigned short* Kb = Kh + (size_t)b * T_ * D_MODEL + h * 64;
    const unsigned short* Vb = Vt + (size_t)bh * 64 * T_;
    const int* mb = mask + b * T_;

    // Q fragments (B-operand for S^T: lane holds Q[q0+r16][kg*8+j])
    bf16x8 qf0 = *(const bf16x8*)(Qb + (size_t)(q0 + r16) * D_MODEL + kg * 8);
    bf16x8 qf1 = *(const bf16x8*)(Qb + (size_t)(q0 + r16) * D_MODEL + 32 + kg * 8);

    float l = 0.f;                       // per-lane partial for q = r16
    f32x4 o[4];
    #pragma unroll
    for (int f = 0; f < 4; ++f) o[f] = (f32x4){0, 0, 0, 0};
    const float sc2 = 0.18033688011112042f;   // log2(e) / sqrt(64)
    const int lim = wave * 16 + r16;          // causal limit on diagonal tile

    const int nT = causal ? (qc + 1) : 32;

    auto stage = [&](int buf, int t) {
        int t0 = t * 64;
        #pragma unroll
        for (int j = 0; j < 2; ++j) {
            int si = j * 256 + tid;
            int row = si >> 3, cg = (si & 7) ^ (row & 7);
            gload_lds16(Kb + (size_t)(t0 + row) * D_MODEL + cg * 8,
                        (char*)Ks[buf] + (j * 256 + wave * 64) * 16);
            gload_lds16(Vb + (size_t)row * T_ + t0 + cg * 8,
                        (char*)Vs[buf] + (j * 256 + wave * 64) * 16);
        }
    };

    stage(0, 0);
    for (int t = 0; t < nT; ++t) {
        __syncthreads();              // stage(t) complete
        if (t + 1 < nT) stage((t + 1) & 1, t + 1);   // prefetch over compute
        const unsigned short* Kst = Ks[t & 1];
        const unsigned short* Vst = Vs[t & 1];
        const int t0 = t * 64;
        const bool diag = causal && (t == qc);

        // key mask for this 64-key tile (wave-uniform)
        unsigned long long km = __ballot(mb[t0 + lane] != 0);

        // ---- S^T = K Q^T ----
        f32x4 s[4];
        #pragma unroll
        for (int c = 0; c < 4; ++c) {
            int key = c * 16 + r16;
            bf16x8 kf0 = *(const bf16x8*)(Kst + key * 64 + ((kg ^ (key & 7)) * 8));
            bf16x8 kf1 = *(const bf16x8*)(Kst + key * 64 + (((4 + kg) ^ (key & 7)) * 8));
            f32x4 z = (f32x4){0, 0, 0, 0};
            z = MFMA(kf0, qf0, z);
            z = MFMA(kf1, qf1, z);
            s[c] = z;
        }

        // ---- exp2 (+ masks only when needed; uniform branch) ----
        float pv[4][4];
        if (!diag && km == ~0ull) {
            #pragma unroll
            for (int c = 0; c < 4; ++c)
                #pragma unroll
                for (int r = 0; r < 4; ++r) {
                    float e = __builtin_amdgcn_exp2f(s[c][r] * sc2);
                    pv[c][r] = e; l += e;
                }
        } else {
            #pragma unroll
            for (int c = 0; c < 4; ++c) {
                unsigned mc = (unsigned)(km >> (c * 16));
                #pragma unroll
                for (int r = 0; r < 4; ++r) {
                    int kbit = kg * 4 + r;
                    bool ok = ((mc >> kbit) & 1) && (!diag || (c * 16 + kbit <= lim));
                    float e = ok ? __builtin_amdgcn_exp2f(s[c][r] * sc2) : 0.f;
                    pv[c][r] = e; l += e;
                }
            }
        }

        // ---- pack into bf16x8 PV A-operands (sigma order) ----
        union pk_t { unsigned u[4]; bf16x8 v; };
        pk_t pa[2];
        #pragma unroll
        for (int c = 0; c < 4; ++c) {
            int half = (c & 1) * 2;
            pa[c >> 1].u[half]     = f32_to_bf16_fast(pv[c][0]) | (f32_to_bf16_fast(pv[c][1]) << 16);
            pa[c >> 1].u[half + 1] = f32_to_bf16_fast(pv[c][2]) | (f32_to_bf16_fast(pv[c][3]) << 16);
        }

        // ---- O += P V: single b128 V-frags (permuted key storage) ----
        #pragma unroll
        for (int f = 0; f < 4; ++f) {
            int row = f * 16 + r16;     // dk row in Vs
            int rx = row & 7;
            #pragma unroll
            for (int cp = 0; cp < 2; ++cp) {
                int g = cp * 4 + kg;    // storage granule = MFMA k-granule
                bf16x8 vf = *(const bf16x8*)(Vst + row * 64 + ((g ^ rx) * 8));
                o[f] = MFMA(pa[cp].v, vf, o[f]);
            }
        }
    }

    // ---- epilogue: reduce l across kg groups, normalize, store [B,T,D] ----
    l += __shfl_xor(l, 16, 64); l += __shfl_xor(l, 32, 64);
    float inv = (l > 0.f) ? 1.0f / l : 0.f;   // every lane: inv for q=r16
    #pragma unroll
    for (int r = 0; r < 4; ++r) {
        int ql = kg * 4 + r;                  // local q row to store
        float iv = __shfl(inv, ql, 64);
        size_t base = ((size_t)(b * T_ + q0 + ql)) * D_MODEL + h * 64;
        #pragma unroll
        for (int f = 0; f < 4; ++f)
            attnout[base + f * 16 + r16] = f32_to_bf16(o[f][r] * iv);
    }
}

// --------------------------- launch -----------------------------------------
extern "C" void kernel_launch(void* const* d_in, const int* in_sizes, int n_in,
                              void* d_out, int out_size, void* d_ws, size_t ws_size,
                              hipStream_t stream) {
    const float* q  = (const float*)d_in[0];
    const float* k  = (const float*)d_in[1];
    const float* v  = (const float*)d_in[2];
    const float* Wq = (const float*)d_in[3];
    const float* bq = (const float*)d_in[4];
    const float* Wk = (const float*)d_in[5];
    const float* bk = (const float*)d_in[6];
    const float* Wv = (const float*)d_in[7];
    const float* bv = (const float*)d_in[8];
    const float* Wo = (const float*)d_in[9];
    const float* bo = (const float*)d_in[10];
    const int* mask   = (const int*)d_in[11];
    const int* causal = (const int*)d_in[12];

    const size_t SZ_TOK = (size_t)M_TOK * D_MODEL;   // 4M elems
    const size_t SZ_W   = (size_t)D_MODEL * D_MODEL; // 1M elems

    unsigned short* qb  = (unsigned short*)d_ws;
    unsigned short* kb  = qb  + SZ_TOK;
    unsigned short* vb  = kb  + SZ_TOK;
    unsigned short* Wqb = vb  + SZ_TOK;
    unsigned short* Wkb = Wqb + SZ_W;
    unsigned short* Wvb = Wkb + SZ_W;
    unsigned short* Wob = Wvb + SZ_W;
    unsigned short* Qhp = Wob + SZ_W;
    unsigned short* Khp = Qhp + SZ_TOK;
    unsigned short* Vtp = Khp + SZ_TOK;
    unsigned short* ab  = Vtp + SZ_TOK;              // 64 MB total

    cvt_all<<<16384, 256, 0, stream>>>(q, k, v, Wq, Wk, Wv, Wo, (ushort4*)qb);

    gemm_qkv<<<dim3(D_MODEL / 128, M_TOK / 128, 3), 256, 0, stream>>>(
        qb, kb, vb, Wqb, Wkb, Wvb, bq, bk, bv, Qhp, Khp, Vtp);

    attn_fwd<<<dim3(32, 32), 256, 0, stream>>>(Qhp, Khp, Vtp, mask, causal, ab);

    gemm_out<<<dim3(D_MODEL / 64, M_TOK / 128), 256, 0, stream>>>(ab, Wob, bo,
                                                                  (float*)d_out);
}